// Round 1
// baseline (3119.402 us; speedup 1.0000x reference)
//
#include <hip/hip_runtime.h>
#include <cstddef>
#include <cstdint>

// Problem constants
constexpr int Bn = 8;
constexpr int Ln = 2048;
constexpr int Dn = 1024;
constexpr float MASKED_VAL = -2147483648.0f;  // -2^31, exact in fp32

// Tile config: 64x64 block tile, BK=32, 256 threads, 4x4 microtile
#define BM 64
#define BN 64
#define BK 32
#define PAD 4

// ---------------------------------------------------------------------------
// Projection: C[m,n] = sum_d X[m,d] * W[n,d] + bias[n]   (torch Linear x@W.T+b)
// M = B*L = 16384, N = D = 1024, K = D = 1024. z selects Q/K/V.
// ---------------------------------------------------------------------------
__global__ __launch_bounds__(256) void proj_kernel(
    const float* __restrict__ Q, const float* __restrict__ K, const float* __restrict__ V,
    const float* __restrict__ Wq, const float* __restrict__ Wk, const float* __restrict__ Wv,
    const float* __restrict__ bq, const float* __restrict__ bk, const float* __restrict__ bv,
    float* __restrict__ Qp, float* __restrict__ Kp, float* __restrict__ Vp)
{
    __shared__ float As[BK][BM + PAD];
    __shared__ float Bs[BK][BN + PAD];

    const float* X; const float* W; const float* bias; float* C;
    if (blockIdx.z == 0)      { X = Q; W = Wq; bias = bq; C = Qp; }
    else if (blockIdx.z == 1) { X = K; W = Wk; bias = bk; C = Kp; }
    else                      { X = V; W = Wv; bias = bv; C = Vp; }

    const int tid = threadIdx.x;
    const int tx = tid & 15, ty = tid >> 4;
    const int m0 = blockIdx.y * BM, n0 = blockIdx.x * BN;

    float acc[4][4] = {};

    for (int k0 = 0; k0 < Dn; k0 += BK) {
        #pragma unroll
        for (int t = 0; t < 2; ++t) {
            int f = tid + t * 256;
            int row = f >> 3;            // 0..63
            int c   = (f & 7) << 2;      // 0,4,..,28
            float4 a = *(const float4*)(X + (size_t)(m0 + row) * Dn + k0 + c);
            As[c + 0][row] = a.x; As[c + 1][row] = a.y;
            As[c + 2][row] = a.z; As[c + 3][row] = a.w;
            float4 b = *(const float4*)(W + (size_t)(n0 + row) * Dn + k0 + c);
            Bs[c + 0][row] = b.x; Bs[c + 1][row] = b.y;
            Bs[c + 2][row] = b.z; Bs[c + 3][row] = b.w;
        }
        __syncthreads();
        #pragma unroll
        for (int kk = 0; kk < BK; ++kk) {
            float4 a4 = *(const float4*)&As[kk][ty << 2];
            float4 b4 = *(const float4*)&Bs[kk][tx << 2];
            float av[4] = {a4.x, a4.y, a4.z, a4.w};
            float bw[4] = {b4.x, b4.y, b4.z, b4.w};
            #pragma unroll
            for (int i = 0; i < 4; ++i)
                #pragma unroll
                for (int j = 0; j < 4; ++j)
                    acc[i][j] = fmaf(av[i], bw[j], acc[i][j]);
        }
        __syncthreads();
    }

    float4 bb = *(const float4*)(bias + n0 + (tx << 2));
    float bias4[4] = {bb.x, bb.y, bb.z, bb.w};
    #pragma unroll
    for (int i = 0; i < 4; ++i) {
        int m = m0 + (ty << 2) + i;
        float4 o;
        o.x = acc[i][0] + bias4[0];
        o.y = acc[i][1] + bias4[1];
        o.z = acc[i][2] + bias4[2];
        o.w = acc[i][3] + bias4[3];
        *(float4*)(C + (size_t)m * Dn + n0 + (tx << 2)) = o;
    }
}

// ---------------------------------------------------------------------------
// Scores: e[b,q,k] = sum_d Qp[b,q,d] * Kp[b,k,d]; masked_fill(k_mask==0, -2^31)
// Written directly to the 'e' output region.
// ---------------------------------------------------------------------------
__global__ __launch_bounds__(256) void score_kernel(
    const float* __restrict__ Qp, const float* __restrict__ Kp,
    const int* __restrict__ k_mask, float* __restrict__ out_e)
{
    __shared__ float As[BK][BM + PAD];
    __shared__ float Bs[BK][BN + PAD];

    const int b = blockIdx.z;
    const int tid = threadIdx.x;
    const int tx = tid & 15, ty = tid >> 4;
    const int m0 = blockIdx.y * BM, n0 = blockIdx.x * BN;

    const float* A  = Qp + (size_t)b * Ln * Dn;
    const float* Bk = Kp + (size_t)b * Ln * Dn;

    float acc[4][4] = {};

    for (int k0 = 0; k0 < Dn; k0 += BK) {
        #pragma unroll
        for (int t = 0; t < 2; ++t) {
            int f = tid + t * 256;
            int row = f >> 3;
            int c   = (f & 7) << 2;
            float4 a = *(const float4*)(A + (size_t)(m0 + row) * Dn + k0 + c);
            As[c + 0][row] = a.x; As[c + 1][row] = a.y;
            As[c + 2][row] = a.z; As[c + 3][row] = a.w;
            float4 bvv = *(const float4*)(Bk + (size_t)(n0 + row) * Dn + k0 + c);
            Bs[c + 0][row] = bvv.x; Bs[c + 1][row] = bvv.y;
            Bs[c + 2][row] = bvv.z; Bs[c + 3][row] = bvv.w;
        }
        __syncthreads();
        #pragma unroll
        for (int kk = 0; kk < BK; ++kk) {
            float4 a4 = *(const float4*)&As[kk][ty << 2];
            float4 b4 = *(const float4*)&Bs[kk][tx << 2];
            float av[4] = {a4.x, a4.y, a4.z, a4.w};
            float bw[4] = {b4.x, b4.y, b4.z, b4.w};
            #pragma unroll
            for (int i = 0; i < 4; ++i)
                #pragma unroll
                for (int j = 0; j < 4; ++j)
                    acc[i][j] = fmaf(av[i], bw[j], acc[i][j]);
        }
        __syncthreads();
    }

    int kmv[4];
    #pragma unroll
    for (int j = 0; j < 4; ++j) kmv[j] = k_mask[b * Ln + n0 + (tx << 2) + j];
    #pragma unroll
    for (int i = 0; i < 4; ++i) {
        int m = m0 + (ty << 2) + i;
        float4 o;
        o.x = kmv[0] ? acc[i][0] : MASKED_VAL;
        o.y = kmv[1] ? acc[i][1] : MASKED_VAL;
        o.z = kmv[2] ? acc[i][2] : MASKED_VAL;
        o.w = kmv[3] ? acc[i][3] : MASKED_VAL;
        *(float4*)(out_e + (size_t)(b * Ln + m) * Ln + n0 + (tx << 2)) = o;
    }
}

// ---------------------------------------------------------------------------
// Row stats: max and 1/sum(exp(e-max)) per (b,q) row. One wave per row.
// Masked entries are -2^31 -> exp underflows to exactly 0.
// ---------------------------------------------------------------------------
__global__ __launch_bounds__(256) void stats_kernel(const float* __restrict__ e,
                                                    float* __restrict__ stats)
{
    const int row  = blockIdx.x * 4 + (threadIdx.x >> 6);   // 0..16383
    const int lane = threadIdx.x & 63;
    const float4* er = (const float4*)(e + (size_t)row * Ln);

    float4 v[8];
    #pragma unroll
    for (int i = 0; i < 8; ++i) v[i] = er[i * 64 + lane];

    float mx = -3.0e38f;
    #pragma unroll
    for (int i = 0; i < 8; ++i)
        mx = fmaxf(mx, fmaxf(fmaxf(v[i].x, v[i].y), fmaxf(v[i].z, v[i].w)));
    #pragma unroll
    for (int o = 32; o > 0; o >>= 1) mx = fmaxf(mx, __shfl_xor(mx, o, 64));

    float s = 0.f;
    #pragma unroll
    for (int i = 0; i < 8; ++i)
        s += __expf(v[i].x - mx) + __expf(v[i].y - mx) +
             __expf(v[i].z - mx) + __expf(v[i].w - mx);
    #pragma unroll
    for (int o = 32; o > 0; o >>= 1) s += __shfl_xor(s, o, 64);

    if (lane == 0) {
        stats[row * 2]     = mx;
        stats[row * 2 + 1] = 1.0f / s;
    }
}

// ---------------------------------------------------------------------------
// PV: a[b,q,d] = sum_k softmax(e)[q,k] * Vp[b,k,d]; zero rows where q_mask==0.
// A-operand (P) built on the fly from e + row stats.
// ---------------------------------------------------------------------------
__global__ __launch_bounds__(256) void pv_kernel(
    const float* __restrict__ e, const float* __restrict__ Vp,
    const float* __restrict__ stats, const int* __restrict__ q_mask,
    float* __restrict__ out_a)
{
    __shared__ float As[BK][BM + PAD];
    __shared__ float Bs[BK][BN + PAD];
    __shared__ float smax[BM];
    __shared__ float sinv[BM];

    const int b = blockIdx.z;
    const int tid = threadIdx.x;
    const int tx = tid & 15, ty = tid >> 4;
    const int m0 = blockIdx.y * BM;   // q tile
    const int n0 = blockIdx.x * BN;   // d tile

    if (tid < BM) {
        int gr = b * Ln + m0 + tid;
        smax[tid] = stats[gr * 2];
        sinv[tid] = stats[gr * 2 + 1];
    }
    __syncthreads();

    const float* eb = e + (size_t)b * Ln * Ln;
    const float* Vb = Vp + (size_t)b * Ln * Dn;

    float acc[4][4] = {};

    for (int k0 = 0; k0 < Ln; k0 += BK) {
        // A tile: 64 q-rows x 32 k-cols of P
        #pragma unroll
        for (int t = 0; t < 2; ++t) {
            int f = tid + t * 256;
            int row = f >> 3;
            int c   = (f & 7) << 2;
            float4 a = *(const float4*)(eb + (size_t)(m0 + row) * Ln + k0 + c);
            float mxr = smax[row], ivr = sinv[row];
            As[c + 0][row] = __expf(a.x - mxr) * ivr;
            As[c + 1][row] = __expf(a.y - mxr) * ivr;
            As[c + 2][row] = __expf(a.z - mxr) * ivr;
            As[c + 3][row] = __expf(a.w - mxr) * ivr;
        }
        // B tile: 32 k-rows x 64 d-cols of Vp (naturally transposed layout)
        #pragma unroll
        for (int t = 0; t < 2; ++t) {
            int f = tid + t * 256;
            int row = f >> 4;            // 0..31 (k)
            int c   = (f & 15) << 2;     // 0..60 (d)
            float4 bvv = *(const float4*)(Vb + (size_t)(k0 + row) * Dn + n0 + c);
            *(float4*)&Bs[row][c] = bvv;
        }
        __syncthreads();
        #pragma unroll
        for (int kk = 0; kk < BK; ++kk) {
            float4 a4 = *(const float4*)&As[kk][ty << 2];
            float4 b4 = *(const float4*)&Bs[kk][tx << 2];
            float av[4] = {a4.x, a4.y, a4.z, a4.w};
            float bw[4] = {b4.x, b4.y, b4.z, b4.w};
            #pragma unroll
            for (int i = 0; i < 4; ++i)
                #pragma unroll
                for (int j = 0; j < 4; ++j)
                    acc[i][j] = fmaf(av[i], bw[j], acc[i][j]);
        }
        __syncthreads();
    }

    #pragma unroll
    for (int i = 0; i < 4; ++i) {
        int m = m0 + (ty << 2) + i;
        int qm = q_mask[b * Ln + m];
        float4 o;
        o.x = qm ? acc[i][0] : 0.f;
        o.y = qm ? acc[i][1] : 0.f;
        o.z = qm ? acc[i][2] : 0.f;
        o.w = qm ? acc[i][3] : 0.f;
        *(float4*)(out_a + (size_t)(b * Ln + m) * Dn + n0 + (tx << 2)) = o;
    }
}

// ---------------------------------------------------------------------------
extern "C" void kernel_launch(void* const* d_in, const int* in_sizes, int n_in,
                              void* d_out, int out_size, void* d_ws, size_t ws_size,
                              hipStream_t stream)
{
    const float* Q  = (const float*)d_in[0];
    const float* K  = (const float*)d_in[1];
    const float* V  = (const float*)d_in[2];
    const float* Wq = (const float*)d_in[3];
    const float* bq = (const float*)d_in[4];
    const float* Wk = (const float*)d_in[5];
    const float* bk = (const float*)d_in[6];
    const float* Wv = (const float*)d_in[7];
    const float* bv = (const float*)d_in[8];
    const int* q_mask = (const int*)d_in[9];
    const int* k_mask = (const int*)d_in[10];

    float* out_a = (float*)d_out;                       // [B, L, D]
    float* out_e = out_a + (size_t)Bn * Ln * Dn;        // [B, L, L]

    // Workspace: Qp | Kp | Vp | stats   (3*64MB + 128KB)
    float* ws    = (float*)d_ws;
    float* Qp    = ws;
    float* Kp    = Qp + (size_t)Bn * Ln * Dn;
    float* Vp    = Kp + (size_t)Bn * Ln * Dn;
    float* stats = Vp + (size_t)Bn * Ln * Dn;

    dim3 blk(256);

    proj_kernel<<<dim3(Dn / BN, (Bn * Ln) / BM, 3), blk, 0, stream>>>(
        Q, K, V, Wq, Wk, Wv, bq, bk, bv, Qp, Kp, Vp);

    score_kernel<<<dim3(Ln / BN, Ln / BM, Bn), blk, 0, stream>>>(
        Qp, Kp, k_mask, out_e);

    stats_kernel<<<dim3((Bn * Ln) / 4), blk, 0, stream>>>(out_e, stats);

    pv_kernel<<<dim3(Dn / BN, Ln / BM, Bn), blk, 0, stream>>>(
        out_e, Vp, stats, q_mask, out_a);
}

// Round 2
// 900.314 us; speedup vs baseline: 3.4648x; 3.4648x over previous
//
#include <hip/hip_runtime.h>
#include <cstddef>
#include <cstdint>

constexpr int Bn = 8;
constexpr int Ln = 2048;
constexpr int Dn = 1024;
constexpr float MASKED_VAL = -2147483648.0f;  // -2^31

typedef unsigned short u16;
typedef unsigned int   u32;
typedef __attribute__((ext_vector_type(8))) __bf16 bf16x8;
typedef __attribute__((ext_vector_type(4))) float  f32x4;

__device__ __forceinline__ u16 f2bf(float x) {
    u32 u = __float_as_uint(x);
    u += 0x7FFFu + ((u >> 16) & 1u);
    return (u16)(u >> 16);
}
__device__ __forceinline__ float bf2f(u16 h) {
    return __uint_as_float(((u32)h) << 16);
}
__device__ __forceinline__ u32 pack2(float a, float b) {
    return (u32)f2bf(a) | ((u32)f2bf(b) << 16);
}

__device__ __forceinline__ void gload16(const void* g, void* l) {
    typedef const __attribute__((address_space(1))) unsigned int* gp_t;
    typedef __attribute__((address_space(3))) unsigned int* lp_t;
    __builtin_amdgcn_global_load_lds((gp_t)g, (lp_t)l, 16, 0, 0);
}

#define MFMA16(a, b, c) __builtin_amdgcn_mfma_f32_16x16x32_bf16((a), (b), (c), 0, 0, 0)

// ---------------------------------------------------------------------------
// proj: C = X @ W^T + bias, split-bf16 3-product GEMM, 128x128 tile, BK=32.
// LDS row (128B) = [hi: 4x16B slots (k0..k0+31)][lo: 4x16B slots], XOR-swizzled.
// Epilogue: z<2 -> write hi+lo bf16; z==2 -> write hi only (V).
// ---------------------------------------------------------------------------
__global__ __launch_bounds__(256) void proj_kernel(
    const float* __restrict__ Q, const float* __restrict__ K, const float* __restrict__ V,
    const float* __restrict__ Wq, const float* __restrict__ Wk, const float* __restrict__ Wv,
    const float* __restrict__ bq, const float* __restrict__ bk, const float* __restrict__ bv,
    u16* __restrict__ Qh, u16* __restrict__ Ql, u16* __restrict__ Kh, u16* __restrict__ Kl,
    u16* __restrict__ Vh)
{
    __shared__ __align__(16) unsigned char As[128 * 128];
    __shared__ __align__(16) unsigned char Bs[128 * 128];

    const int z = blockIdx.z;
    const float* X; const float* W; const float* bias;
    u16* outH; u16* outL;
    if (z == 0)      { X = Q; W = Wq; bias = bq; outH = Qh; outL = Ql; }
    else if (z == 1) { X = K; W = Wk; bias = bk; outH = Kh; outL = Kl; }
    else             { X = V; W = Wv; bias = bv; outH = Vh; outL = nullptr; }

    const int m0 = blockIdx.y * 128, n0 = blockIdx.x * 128;
    const int tid = threadIdx.x, lane = tid & 63, wid = tid >> 6;
    const int wm = (wid >> 1) * 64, wn = (wid & 1) * 64;

    // staging: each thread converts one (row, 16-k half) of A and of B
    const int srow = tid >> 1, half = tid & 1;
    const float* srcA = X + (size_t)(m0 + srow) * Dn + half * 16;
    const float* srcB = W + (size_t)(n0 + srow) * Dn + half * 16;
    unsigned char* wA = As + srow * 128;
    unsigned char* wB = Bs + srow * 128;
    const int sw = srow & 7;
    const int sH0 = ((half * 2 + 0) ^ sw) << 4, sH1 = ((half * 2 + 1) ^ sw) << 4;
    const int sL0 = ((half * 2 + 4) ^ sw) << 4, sL1 = ((half * 2 + 5) ^ sw) << 4;

    f32x4 acc[4][4];
    const f32x4 z4 = {0.f, 0.f, 0.f, 0.f};
    #pragma unroll
    for (int i = 0; i < 4; ++i)
        #pragma unroll
        for (int j = 0; j < 4; ++j) acc[i][j] = z4;

    for (int k0 = 0; k0 < Dn; k0 += 32) {
        float fa[16], fw[16];
        *(float4*)&fa[0]  = *(const float4*)(srcA + 0);
        *(float4*)&fa[4]  = *(const float4*)(srcA + 4);
        *(float4*)&fa[8]  = *(const float4*)(srcA + 8);
        *(float4*)&fa[12] = *(const float4*)(srcA + 12);
        *(float4*)&fw[0]  = *(const float4*)(srcB + 0);
        *(float4*)&fw[4]  = *(const float4*)(srcB + 4);
        *(float4*)&fw[8]  = *(const float4*)(srcB + 8);
        *(float4*)&fw[12] = *(const float4*)(srcB + 12);
        srcA += 32; srcB += 32;

        u32 ha[8], la[8], hb[8], lb[8];
        #pragma unroll
        for (int i = 0; i < 8; ++i) {
            float x0 = fa[2*i], x1 = fa[2*i+1];
            u16 h0 = f2bf(x0), h1 = f2bf(x1);
            ha[i] = (u32)h0 | ((u32)h1 << 16);
            la[i] = (u32)f2bf(x0 - bf2f(h0)) | ((u32)f2bf(x1 - bf2f(h1)) << 16);
            float y0 = fw[2*i], y1 = fw[2*i+1];
            u16 g0 = f2bf(y0), g1 = f2bf(y1);
            hb[i] = (u32)g0 | ((u32)g1 << 16);
            lb[i] = (u32)f2bf(y0 - bf2f(g0)) | ((u32)f2bf(y1 - bf2f(g1)) << 16);
        }
        *(uint4*)(wA + sH0) = make_uint4(ha[0], ha[1], ha[2], ha[3]);
        *(uint4*)(wA + sH1) = make_uint4(ha[4], ha[5], ha[6], ha[7]);
        *(uint4*)(wA + sL0) = make_uint4(la[0], la[1], la[2], la[3]);
        *(uint4*)(wA + sL1) = make_uint4(la[4], la[5], la[6], la[7]);
        *(uint4*)(wB + sH0) = make_uint4(hb[0], hb[1], hb[2], hb[3]);
        *(uint4*)(wB + sH1) = make_uint4(hb[4], hb[5], hb[6], hb[7]);
        *(uint4*)(wB + sL0) = make_uint4(lb[0], lb[1], lb[2], lb[3]);
        *(uint4*)(wB + sL1) = make_uint4(lb[4], lb[5], lb[6], lb[7]);
        __syncthreads();

        bf16x8 ah[4], al[4], bh[4], bl[4];
        const int sh = lane >> 4;
        #pragma unroll
        for (int i = 0; i < 4; ++i) {
            int row = wm + i * 16 + (lane & 15);
            const unsigned char* base = As + row * 128;
            ah[i] = *(const bf16x8*)(base + ((sh       ^ (row & 7)) << 4));
            al[i] = *(const bf16x8*)(base + (((sh + 4) ^ (row & 7)) << 4));
        }
        #pragma unroll
        for (int j = 0; j < 4; ++j) {
            int row = wn + j * 16 + (lane & 15);
            const unsigned char* base = Bs + row * 128;
            bh[j] = *(const bf16x8*)(base + ((sh       ^ (row & 7)) << 4));
            bl[j] = *(const bf16x8*)(base + (((sh + 4) ^ (row & 7)) << 4));
        }
        #pragma unroll
        for (int i = 0; i < 4; ++i)
            #pragma unroll
            for (int j = 0; j < 4; ++j) {
                acc[i][j] = MFMA16(ah[i], bh[j], acc[i][j]);
                acc[i][j] = MFMA16(ah[i], bl[j], acc[i][j]);
                acc[i][j] = MFMA16(al[i], bh[j], acc[i][j]);
            }
        __syncthreads();
    }

    float bv4[4];
    #pragma unroll
    for (int j = 0; j < 4; ++j) bv4[j] = bias[n0 + wn + j * 16 + (lane & 15)];
    #pragma unroll
    for (int i = 0; i < 4; ++i) {
        #pragma unroll
        for (int r = 0; r < 4; ++r) {
            int m = m0 + wm + i * 16 + (lane >> 4) * 4 + r;
            u16* oh = outH + (size_t)m * Dn + n0 + wn;
            u16* ol = outL ? outL + (size_t)m * Dn + n0 + wn : nullptr;
            #pragma unroll
            for (int j = 0; j < 4; ++j) {
                float v = acc[i][j][r] + bv4[j];
                u16 h = f2bf(v);
                oh[j * 16 + (lane & 15)] = h;
                if (ol) ol[j * 16 + (lane & 15)] = f2bf(v - bf2f(h));
            }
        }
    }
}

// ---------------------------------------------------------------------------
// vtrans: Vh [B*L][D] bf16 -> Vt [B][D][L] bf16 (LDS-tiled 64x64)
// ---------------------------------------------------------------------------
__global__ __launch_bounds__(256) void vtrans_kernel(const u16* __restrict__ Vh,
                                                     u16* __restrict__ Vt)
{
    __shared__ u16 tile[64][72];
    const int b = blockIdx.z;
    const int l0 = blockIdx.y * 64, d0 = blockIdx.x * 64;
    const int t = threadIdx.x;
    const int r = t >> 2, cq = (t & 3) * 16;

    const u16* src = Vh + (size_t)(b * Ln + l0 + r) * Dn + d0 + cq;
    *(uint4*)&tile[r][cq]     = *(const uint4*)(src);
    *(uint4*)&tile[r][cq + 8] = *(const uint4*)(src + 8);
    __syncthreads();

    u16 tmp[16];
    #pragma unroll
    for (int i = 0; i < 16; ++i) tmp[i] = tile[cq + i][r];
    u16* dst = Vt + (size_t)b * Dn * Ln + (size_t)(d0 + r) * Ln + l0 + cq;
    *(uint4*)(dst)     = *(uint4*)&tmp[0];
    *(uint4*)(dst + 8) = *(uint4*)&tmp[8];
}

// ---------------------------------------------------------------------------
// score: e = Qp @ Kp^T (split-bf16, 3 products), mask -> -2^31, write e.
// global_load_lds staging with pre-swizzled source (rule #21).
// ---------------------------------------------------------------------------
__global__ __launch_bounds__(256) void score_kernel(
    const u16* __restrict__ Qh, const u16* __restrict__ Ql,
    const u16* __restrict__ Kh, const u16* __restrict__ Kl,
    const int* __restrict__ k_mask, float* __restrict__ out_e)
{
    __shared__ __align__(16) unsigned char As[128 * 128];
    __shared__ __align__(16) unsigned char Bs[128 * 128];

    const int b = blockIdx.z;
    const int m0 = blockIdx.y * 128, n0 = blockIdx.x * 128;
    const int tid = threadIdx.x, lane = tid & 63, wid = tid >> 6;
    const int wm = (wid >> 1) * 64, wn = (wid & 1) * 64;

    const size_t boff = (size_t)b * Ln * Dn;
    const u16* Qh_b = Qh + boff; const u16* Ql_b = Ql + boff;
    const u16* Kh_b = Kh + boff; const u16* Kl_b = Kl + boff;

    const u16* gA[4]; const u16* gB[4]; int ldsOff[4];
    #pragma unroll
    for (int q = 0; q < 4; ++q) {
        int c = wid * 4 + q;
        int row = c * 8 + (lane >> 3);
        int sig = (lane & 7) ^ (row & 7);
        const u16* aB = (sig < 4) ? Qh_b : Ql_b;
        const u16* bB = (sig < 4) ? Kh_b : Kl_b;
        gA[q] = aB + (size_t)(m0 + row) * Dn + (sig & 3) * 8;
        gB[q] = bB + (size_t)(n0 + row) * Dn + (sig & 3) * 8;
        ldsOff[q] = c * 1024;
    }

    f32x4 acc[4][4];
    const f32x4 z4 = {0.f, 0.f, 0.f, 0.f};
    #pragma unroll
    for (int i = 0; i < 4; ++i)
        #pragma unroll
        for (int j = 0; j < 4; ++j) acc[i][j] = z4;

    for (int k0 = 0; k0 < Dn; k0 += 32) {
        #pragma unroll
        for (int q = 0; q < 4; ++q) {
            gload16(gA[q], As + ldsOff[q]);
            gload16(gB[q], Bs + ldsOff[q]);
            gA[q] += 32; gB[q] += 32;
        }
        __syncthreads();

        bf16x8 ah[4], al[4], bh[4], bl[4];
        const int sh = lane >> 4;
        #pragma unroll
        for (int i = 0; i < 4; ++i) {
            int row = wm + i * 16 + (lane & 15);
            const unsigned char* base = As + row * 128;
            ah[i] = *(const bf16x8*)(base + ((sh       ^ (row & 7)) << 4));
            al[i] = *(const bf16x8*)(base + (((sh + 4) ^ (row & 7)) << 4));
        }
        #pragma unroll
        for (int j = 0; j < 4; ++j) {
            int row = wn + j * 16 + (lane & 15);
            const unsigned char* base = Bs + row * 128;
            bh[j] = *(const bf16x8*)(base + ((sh       ^ (row & 7)) << 4));
            bl[j] = *(const bf16x8*)(base + (((sh + 4) ^ (row & 7)) << 4));
        }
        #pragma unroll
        for (int i = 0; i < 4; ++i)
            #pragma unroll
            for (int j = 0; j < 4; ++j) {
                acc[i][j] = MFMA16(ah[i], bh[j], acc[i][j]);
                acc[i][j] = MFMA16(ah[i], bl[j], acc[i][j]);
                acc[i][j] = MFMA16(al[i], bh[j], acc[i][j]);
            }
        __syncthreads();
    }

    int km[4];
    #pragma unroll
    for (int j = 0; j < 4; ++j) km[j] = k_mask[b * Ln + n0 + wn + j * 16 + (lane & 15)];
    #pragma unroll
    for (int i = 0; i < 4; ++i) {
        #pragma unroll
        for (int r = 0; r < 4; ++r) {
            int m = m0 + wm + i * 16 + (lane >> 4) * 4 + r;
            float* orow = out_e + ((size_t)(b * Ln + m)) * Ln + n0 + wn;
            #pragma unroll
            for (int j = 0; j < 4; ++j)
                orow[j * 16 + (lane & 15)] = km[j] ? acc[i][j][r] : MASKED_VAL;
        }
    }
}

// ---------------------------------------------------------------------------
// stats: per-row max and 1/sum(exp(e-max)). One wave per row.
// ---------------------------------------------------------------------------
__global__ __launch_bounds__(256) void stats_kernel(const float* __restrict__ e,
                                                    float* __restrict__ stats)
{
    const int row  = blockIdx.x * 4 + (threadIdx.x >> 6);
    const int lane = threadIdx.x & 63;
    const float4* er = (const float4*)(e + (size_t)row * Ln);

    float4 v[8];
    #pragma unroll
    for (int i = 0; i < 8; ++i) v[i] = er[i * 64 + lane];

    float mx = -3.0e38f;
    #pragma unroll
    for (int i = 0; i < 8; ++i)
        mx = fmaxf(mx, fmaxf(fmaxf(v[i].x, v[i].y), fmaxf(v[i].z, v[i].w)));
    #pragma unroll
    for (int o = 32; o > 0; o >>= 1) mx = fmaxf(mx, __shfl_xor(mx, o, 64));

    float s = 0.f;
    #pragma unroll
    for (int i = 0; i < 8; ++i)
        s += __expf(v[i].x - mx) + __expf(v[i].y - mx) +
             __expf(v[i].z - mx) + __expf(v[i].w - mx);
    #pragma unroll
    for (int o = 32; o > 0; o >>= 1) s += __shfl_xor(s, o, 64);

    if (lane == 0) {
        stats[row * 2]     = mx;
        stats[row * 2 + 1] = 1.0f / s;
    }
}

// ---------------------------------------------------------------------------
// pv: a = softmax(e) @ Vp, zero q_mask==0 rows. A=P on the fly (bf16),
// B=Vt via gload_lds. BK=64, single product.
// ---------------------------------------------------------------------------
__global__ __launch_bounds__(256) void pv_kernel(
    const float* __restrict__ e, const u16* __restrict__ Vt,
    const float* __restrict__ stats, const int* __restrict__ q_mask,
    float* __restrict__ out_a)
{
    __shared__ __align__(16) unsigned char As[128 * 128];
    __shared__ __align__(16) unsigned char Bs[128 * 128];

    const int b = blockIdx.z;
    const int m0 = blockIdx.y * 128;   // q tile
    const int n0 = blockIdx.x * 128;   // d tile
    const int tid = threadIdx.x, lane = tid & 63, wid = tid >> 6;
    const int wm = (wid >> 1) * 64, wn = (wid & 1) * 64;

    const float* e_b  = e  + (size_t)b * Ln * Ln;
    const u16*   Vt_b = Vt + (size_t)b * Dn * Ln;

    const int srow = tid >> 1, half = tid & 1;
    const float* srcE = e_b + (size_t)(m0 + srow) * Ln + half * 32;
    const float smx  = stats[(b * Ln + m0 + srow) * 2];
    const float sinv = stats[(b * Ln + m0 + srow) * 2 + 1];
    unsigned char* wA = As + srow * 128;
    int sl[4];
    #pragma unroll
    for (int c = 0; c < 4; ++c) sl[c] = (((half * 4 + c) ^ (srow & 7)) << 4);

    const u16* gB[4];
    #pragma unroll
    for (int q = 0; q < 4; ++q) {
        int c = wid * 4 + q;
        int row = c * 8 + (lane >> 3);
        int sig = (lane & 7) ^ (row & 7);
        gB[q] = Vt_b + (size_t)(n0 + row) * Ln + sig * 8;
    }

    f32x4 acc[4][4];
    const f32x4 z4 = {0.f, 0.f, 0.f, 0.f};
    #pragma unroll
    for (int i = 0; i < 4; ++i)
        #pragma unroll
        for (int j = 0; j < 4; ++j) acc[i][j] = z4;

    for (int k0 = 0; k0 < Ln; k0 += 64) {
        #pragma unroll
        for (int q = 0; q < 4; ++q) {
            gload16(gB[q], Bs + (wid * 4 + q) * 1024);
            gB[q] += 64;
        }
        float fe[32];
        #pragma unroll
        for (int c = 0; c < 8; ++c) *(float4*)&fe[c * 4] = *(const float4*)(srcE + c * 4);
        srcE += 64;
        #pragma unroll
        for (int c = 0; c < 4; ++c) {
            u32 p0 = pack2(__expf(fe[c*8+0] - smx) * sinv, __expf(fe[c*8+1] - smx) * sinv);
            u32 p1 = pack2(__expf(fe[c*8+2] - smx) * sinv, __expf(fe[c*8+3] - smx) * sinv);
            u32 p2 = pack2(__expf(fe[c*8+4] - smx) * sinv, __expf(fe[c*8+5] - smx) * sinv);
            u32 p3 = pack2(__expf(fe[c*8+6] - smx) * sinv, __expf(fe[c*8+7] - smx) * sinv);
            *(uint4*)(wA + sl[c]) = make_uint4(p0, p1, p2, p3);
        }
        __syncthreads();

        const int sh = lane >> 4;
        #pragma unroll
        for (int s = 0; s < 2; ++s) {
            bf16x8 af[4], bv[4];
            #pragma unroll
            for (int i = 0; i < 4; ++i) {
                int row = wm + i * 16 + (lane & 15);
                af[i] = *(const bf16x8*)(As + row * 128 + (((s * 4 + sh) ^ (row & 7)) << 4));
            }
            #pragma unroll
            for (int j = 0; j < 4; ++j) {
                int row = wn + j * 16 + (lane & 15);
                bv[j] = *(const bf16x8*)(Bs + row * 128 + (((s * 4 + sh) ^ (row & 7)) << 4));
            }
            #pragma unroll
            for (int i = 0; i < 4; ++i)
                #pragma unroll
                for (int j = 0; j < 4; ++j)
                    acc[i][j] = MFMA16(af[i], bv[j], acc[i][j]);
        }
        __syncthreads();
    }

    #pragma unroll
    for (int i = 0; i < 4; ++i) {
        #pragma unroll
        for (int r = 0; r < 4; ++r) {
            int m = m0 + wm + i * 16 + (lane >> 4) * 4 + r;
            int qm = q_mask[b * Ln + m];
            float* orow = out_a + (size_t)(b * Ln + m) * Dn + n0 + wn;
            #pragma unroll
            for (int j = 0; j < 4; ++j)
                orow[j * 16 + (lane & 15)] = qm ? acc[i][j][r] : 0.0f;
        }
    }
}

// ---------------------------------------------------------------------------
extern "C" void kernel_launch(void* const* d_in, const int* in_sizes, int n_in,
                              void* d_out, int out_size, void* d_ws, size_t ws_size,
                              hipStream_t stream)
{
    const float* Q  = (const float*)d_in[0];
    const float* K  = (const float*)d_in[1];
    const float* V  = (const float*)d_in[2];
    const float* Wq = (const float*)d_in[3];
    const float* bq = (const float*)d_in[4];
    const float* Wk = (const float*)d_in[5];
    const float* bk = (const float*)d_in[6];
    const float* Wv = (const float*)d_in[7];
    const float* bv = (const float*)d_in[8];
    const int* q_mask = (const int*)d_in[9];
    const int* k_mask = (const int*)d_in[10];

    float* out_a = (float*)d_out;                       // [B, L, D]
    float* out_e = out_a + (size_t)Bn * Ln * Dn;        // [B, L, L]

    const size_t NE = (size_t)Bn * Ln * Dn;             // 16.7M elems
    u16* Qh = (u16*)d_ws;
    u16* Ql = Qh + NE;
    u16* Kh = Ql + NE;
    u16* Kl = Kh + NE;
    u16* Vh = Kl + NE;
    u16* Vt = Vh + NE;
    float* stats = (float*)(Vt + NE);

    dim3 blk(256);

    proj_kernel<<<dim3(Dn / 128, (Bn * Ln) / 128, 3), blk, 0, stream>>>(
        Q, K, V, Wq, Wk, Wv, bq, bk, bv, Qh, Ql, Kh, Kl, Vh);

    vtrans_kernel<<<dim3(Dn / 64, Ln / 64, Bn), blk, 0, stream>>>(Vh, Vt);

    score_kernel<<<dim3(Ln / 128, Ln / 128, Bn), blk, 0, stream>>>(
        Qh, Ql, Kh, Kl, k_mask, out_e);

    stats_kernel<<<dim3((Bn * Ln) / 4), blk, 0, stream>>>(out_e, stats);

    pv_kernel<<<dim3(Dn / 128, Ln / 128, Bn), blk, 0, stream>>>(
        out_e, Vt, stats, q_mask, out_a);
}

// Round 3
// 829.422 us; speedup vs baseline: 3.7609x; 1.0855x over previous
//
#include <hip/hip_runtime.h>
#include <cstddef>
#include <cstdint>

constexpr int Bn = 8;
constexpr int Ln = 2048;
constexpr int Dn = 1024;
constexpr float MASKED_VAL = -2147483648.0f;  // -2^31

typedef unsigned short u16;
typedef unsigned int   u32;
typedef __attribute__((ext_vector_type(8))) __bf16 bf16x8;
typedef __attribute__((ext_vector_type(4))) float  f32x4;

__device__ __forceinline__ u16 f2bf(float x) {
    u32 u = __float_as_uint(x);
    u += 0x7FFFu + ((u >> 16) & 1u);
    return (u16)(u >> 16);
}
__device__ __forceinline__ float bf2f(u16 h) {
    return __uint_as_float(((u32)h) << 16);
}
__device__ __forceinline__ u32 pack2(float a, float b) {
    return (u32)f2bf(a) | ((u32)f2bf(b) << 16);
}

__device__ __forceinline__ void gload16(const void* g, void* l) {
    typedef const __attribute__((address_space(1))) unsigned int* gp_t;
    typedef __attribute__((address_space(3))) unsigned int* lp_t;
    __builtin_amdgcn_global_load_lds((gp_t)g, (lp_t)l, 16, 0, 0);
}

#define MFMA16(a, b, c) __builtin_amdgcn_mfma_f32_16x16x32_bf16((a), (b), (c), 0, 0, 0)

// ---------------------------------------------------------------------------
// convert_split: fp32 -> (hi, lo) bf16.  8 elems/thread, exact grid.
// ---------------------------------------------------------------------------
__global__ __launch_bounds__(256) void convert_split_kernel(
    const float* __restrict__ src, u16* __restrict__ dh, u16* __restrict__ dl, int n)
{
    int i = (blockIdx.x * 256 + threadIdx.x) * 8;
    if (i >= n) return;
    float f[8];
    *(float4*)&f[0] = *(const float4*)(src + i);
    *(float4*)&f[4] = *(const float4*)(src + i + 4);
    u32 H[4], L[4];
    #pragma unroll
    for (int j = 0; j < 4; ++j) {
        float x0 = f[2*j], x1 = f[2*j+1];
        u16 h0 = f2bf(x0), h1 = f2bf(x1);
        H[j] = (u32)h0 | ((u32)h1 << 16);
        L[j] = (u32)f2bf(x0 - bf2f(h0)) | ((u32)f2bf(x1 - bf2f(h1)) << 16);
    }
    *(uint4*)(dh + i) = make_uint4(H[0], H[1], H[2], H[3]);
    *(uint4*)(dl + i) = make_uint4(L[0], L[1], L[2], L[3]);
}

__global__ __launch_bounds__(256) void convert_single_kernel(
    const float* __restrict__ src, u16* __restrict__ dh, int n)
{
    int i = (blockIdx.x * 256 + threadIdx.x) * 8;
    if (i >= n) return;
    float f[8];
    *(float4*)&f[0] = *(const float4*)(src + i);
    *(float4*)&f[4] = *(const float4*)(src + i + 4);
    u32 H[4];
    #pragma unroll
    for (int j = 0; j < 4; ++j) H[j] = pack2(f[2*j], f[2*j+1]);
    *(uint4*)(dh + i) = make_uint4(H[0], H[1], H[2], H[3]);
}

// ---------------------------------------------------------------------------
// projqk: C = X @ W^T + bias in split-bf16 (3 products), gload_lds staging.
// z=0 -> Q, z=1 -> K. Outputs hi+lo bf16. Bit-identical to round-2 proj math.
// LDS row (128B) = [4 hi slots | 4 lo slots] covering k-chunk of 32, swizzled.
// ---------------------------------------------------------------------------
__global__ __launch_bounds__(256) void projqk_kernel(
    const u16* __restrict__ Xhq, const u16* __restrict__ Xlq,
    const u16* __restrict__ Xhk, const u16* __restrict__ Xlk,
    const u16* __restrict__ Whq, const u16* __restrict__ Wlq,
    const u16* __restrict__ Whk, const u16* __restrict__ Wlk,
    const float* __restrict__ bq, const float* __restrict__ bk,
    u16* __restrict__ Qh, u16* __restrict__ Ql,
    u16* __restrict__ Kh, u16* __restrict__ Kl)
{
    __shared__ __align__(16) unsigned char As[128 * 128];
    __shared__ __align__(16) unsigned char Bs[128 * 128];

    const int z = blockIdx.z;
    const u16* Xh = z ? Xhk : Xhq;  const u16* Xl = z ? Xlk : Xlq;
    const u16* Wh = z ? Whk : Whq;  const u16* Wl = z ? Wlk : Wlq;
    const float* bias = z ? bk : bq;
    u16* outH = z ? Kh : Qh;        u16* outL = z ? Kl : Ql;

    const int m0 = blockIdx.y * 128, n0 = blockIdx.x * 128;
    const int tid = threadIdx.x, lane = tid & 63, wid = tid >> 6;
    const int wm = (wid >> 1) * 64, wn = (wid & 1) * 64;

    const u16* gA[4]; const u16* gB[4]; int ldsOff[4];
    #pragma unroll
    for (int q = 0; q < 4; ++q) {
        int c = wid * 4 + q;
        int row = c * 8 + (lane >> 3);
        int sig = (lane & 7) ^ (row & 7);
        const u16* aB = (sig < 4) ? Xh : Xl;
        const u16* bB = (sig < 4) ? Wh : Wl;
        gA[q] = aB + (size_t)(m0 + row) * Dn + (sig & 3) * 8;
        gB[q] = bB + (size_t)(n0 + row) * Dn + (sig & 3) * 8;
        ldsOff[q] = c * 1024;
    }

    f32x4 acc[4][4];
    const f32x4 z4 = {0.f, 0.f, 0.f, 0.f};
    #pragma unroll
    for (int i = 0; i < 4; ++i)
        #pragma unroll
        for (int j = 0; j < 4; ++j) acc[i][j] = z4;

    for (int k0 = 0; k0 < Dn; k0 += 32) {
        #pragma unroll
        for (int q = 0; q < 4; ++q) {
            gload16(gA[q], As + ldsOff[q]);
            gload16(gB[q], Bs + ldsOff[q]);
            gA[q] += 32; gB[q] += 32;
        }
        __syncthreads();

        bf16x8 ah[4], al[4], bh[4], bl[4];
        const int sh = lane >> 4;
        #pragma unroll
        for (int i = 0; i < 4; ++i) {
            int row = wm + i * 16 + (lane & 15);
            const unsigned char* base = As + row * 128;
            ah[i] = *(const bf16x8*)(base + ((sh       ^ (row & 7)) << 4));
            al[i] = *(const bf16x8*)(base + (((sh + 4) ^ (row & 7)) << 4));
        }
        #pragma unroll
        for (int j = 0; j < 4; ++j) {
            int row = wn + j * 16 + (lane & 15);
            const unsigned char* base = Bs + row * 128;
            bh[j] = *(const bf16x8*)(base + ((sh       ^ (row & 7)) << 4));
            bl[j] = *(const bf16x8*)(base + (((sh + 4) ^ (row & 7)) << 4));
        }
        #pragma unroll
        for (int i = 0; i < 4; ++i)
            #pragma unroll
            for (int j = 0; j < 4; ++j) {
                acc[i][j] = MFMA16(ah[i], bh[j], acc[i][j]);
                acc[i][j] = MFMA16(ah[i], bl[j], acc[i][j]);
                acc[i][j] = MFMA16(al[i], bh[j], acc[i][j]);
            }
        __syncthreads();
    }

    float bv4[4];
    #pragma unroll
    for (int j = 0; j < 4; ++j) bv4[j] = bias[n0 + wn + j * 16 + (lane & 15)];
    #pragma unroll
    for (int i = 0; i < 4; ++i) {
        #pragma unroll
        for (int r = 0; r < 4; ++r) {
            int m = m0 + wm + i * 16 + (lane >> 4) * 4 + r;
            u16* oh = outH + (size_t)m * Dn + n0 + wn;
            u16* ol = outL + (size_t)m * Dn + n0 + wn;
            #pragma unroll
            for (int j = 0; j < 4; ++j) {
                float v = acc[i][j][r] + bv4[j];
                u16 h = f2bf(v);
                oh[j * 16 + (lane & 15)] = h;
                ol[j * 16 + (lane & 15)] = f2bf(v - bf2f(h));
            }
        }
    }
}

// ---------------------------------------------------------------------------
// projv: Vp = V @ Wv^T + bv, single-product bf16, BK=64, gload_lds staging.
// LDS row (128B) = 8 slots covering k-chunk of 64, swizzled.
// ---------------------------------------------------------------------------
__global__ __launch_bounds__(256) void projv_kernel(
    const u16* __restrict__ Xv, const u16* __restrict__ Wv,
    const float* __restrict__ bv, u16* __restrict__ Vh)
{
    __shared__ __align__(16) unsigned char As[128 * 128];
    __shared__ __align__(16) unsigned char Bs[128 * 128];

    const int m0 = blockIdx.y * 128, n0 = blockIdx.x * 128;
    const int tid = threadIdx.x, lane = tid & 63, wid = tid >> 6;
    const int wm = (wid >> 1) * 64, wn = (wid & 1) * 64;

    const u16* gA[4]; const u16* gB[4]; int ldsOff[4];
    #pragma unroll
    for (int q = 0; q < 4; ++q) {
        int c = wid * 4 + q;
        int row = c * 8 + (lane >> 3);
        int sig = (lane & 7) ^ (row & 7);
        gA[q] = Xv + (size_t)(m0 + row) * Dn + sig * 8;
        gB[q] = Wv + (size_t)(n0 + row) * Dn + sig * 8;
        ldsOff[q] = c * 1024;
    }

    f32x4 acc[4][4];
    const f32x4 z4 = {0.f, 0.f, 0.f, 0.f};
    #pragma unroll
    for (int i = 0; i < 4; ++i)
        #pragma unroll
        for (int j = 0; j < 4; ++j) acc[i][j] = z4;

    for (int k0 = 0; k0 < Dn; k0 += 64) {
        #pragma unroll
        for (int q = 0; q < 4; ++q) {
            gload16(gA[q], As + ldsOff[q]);
            gload16(gB[q], Bs + ldsOff[q]);
            gA[q] += 64; gB[q] += 64;
        }
        __syncthreads();

        const int sh = lane >> 4;
        #pragma unroll
        for (int s = 0; s < 2; ++s) {
            bf16x8 af[4], bf[4];
            #pragma unroll
            for (int i = 0; i < 4; ++i) {
                int row = wm + i * 16 + (lane & 15);
                af[i] = *(const bf16x8*)(As + row * 128 + (((s * 4 + sh) ^ (row & 7)) << 4));
            }
            #pragma unroll
            for (int j = 0; j < 4; ++j) {
                int row = wn + j * 16 + (lane & 15);
                bf[j] = *(const bf16x8*)(Bs + row * 128 + (((s * 4 + sh) ^ (row & 7)) << 4));
            }
            #pragma unroll
            for (int i = 0; i < 4; ++i)
                #pragma unroll
                for (int j = 0; j < 4; ++j)
                    acc[i][j] = MFMA16(af[i], bf[j], acc[i][j]);
        }
        __syncthreads();
    }

    float bv4[4];
    #pragma unroll
    for (int j = 0; j < 4; ++j) bv4[j] = bv[n0 + wn + j * 16 + (lane & 15)];
    #pragma unroll
    for (int i = 0; i < 4; ++i) {
        #pragma unroll
        for (int r = 0; r < 4; ++r) {
            int m = m0 + wm + i * 16 + (lane >> 4) * 4 + r;
            u16* oh = Vh + (size_t)m * Dn + n0 + wn;
            #pragma unroll
            for (int j = 0; j < 4; ++j)
                oh[j * 16 + (lane & 15)] = f2bf(acc[i][j][r] + bv4[j]);
        }
    }
}

// ---------------------------------------------------------------------------
// vtrans: Vh [B*L][D] bf16 -> Vt [B][D][L] bf16 (LDS-tiled 64x64)
// ---------------------------------------------------------------------------
__global__ __launch_bounds__(256) void vtrans_kernel(const u16* __restrict__ Vh,
                                                     u16* __restrict__ Vt)
{
    __shared__ u16 tile[64][72];
    const int b = blockIdx.z;
    const int l0 = blockIdx.y * 64, d0 = blockIdx.x * 64;
    const int t = threadIdx.x;
    const int r = t >> 2, cq = (t & 3) * 16;

    const u16* src = Vh + (size_t)(b * Ln + l0 + r) * Dn + d0 + cq;
    *(uint4*)&tile[r][cq]     = *(const uint4*)(src);
    *(uint4*)&tile[r][cq + 8] = *(const uint4*)(src + 8);
    __syncthreads();

    u16 tmp[16];
    #pragma unroll
    for (int i = 0; i < 16; ++i) tmp[i] = tile[cq + i][r];
    u16* dst = Vt + (size_t)b * Dn * Ln + (size_t)(d0 + r) * Ln + l0 + cq;
    *(uint4*)(dst)     = *(uint4*)&tmp[0];
    *(uint4*)(dst + 8) = *(uint4*)&tmp[8];
}

// ---------------------------------------------------------------------------
// score: e = Qp @ Kp^T (split-bf16, 3 products), mask -> -2^31, write e.
// ---------------------------------------------------------------------------
__global__ __launch_bounds__(256) void score_kernel(
    const u16* __restrict__ Qh, const u16* __restrict__ Ql,
    const u16* __restrict__ Kh, const u16* __restrict__ Kl,
    const int* __restrict__ k_mask, float* __restrict__ out_e)
{
    __shared__ __align__(16) unsigned char As[128 * 128];
    __shared__ __align__(16) unsigned char Bs[128 * 128];

    const int b = blockIdx.z;
    const int m0 = blockIdx.y * 128, n0 = blockIdx.x * 128;
    const int tid = threadIdx.x, lane = tid & 63, wid = tid >> 6;
    const int wm = (wid >> 1) * 64, wn = (wid & 1) * 64;

    const size_t boff = (size_t)b * Ln * Dn;
    const u16* Qh_b = Qh + boff; const u16* Ql_b = Ql + boff;
    const u16* Kh_b = Kh + boff; const u16* Kl_b = Kl + boff;

    const u16* gA[4]; const u16* gB[4]; int ldsOff[4];
    #pragma unroll
    for (int q = 0; q < 4; ++q) {
        int c = wid * 4 + q;
        int row = c * 8 + (lane >> 3);
        int sig = (lane & 7) ^ (row & 7);
        const u16* aB = (sig < 4) ? Qh_b : Ql_b;
        const u16* bB = (sig < 4) ? Kh_b : Kl_b;
        gA[q] = aB + (size_t)(m0 + row) * Dn + (sig & 3) * 8;
        gB[q] = bB + (size_t)(n0 + row) * Dn + (sig & 3) * 8;
        ldsOff[q] = c * 1024;
    }

    f32x4 acc[4][4];
    const f32x4 z4 = {0.f, 0.f, 0.f, 0.f};
    #pragma unroll
    for (int i = 0; i < 4; ++i)
        #pragma unroll
        for (int j = 0; j < 4; ++j) acc[i][j] = z4;

    for (int k0 = 0; k0 < Dn; k0 += 32) {
        #pragma unroll
        for (int q = 0; q < 4; ++q) {
            gload16(gA[q], As + ldsOff[q]);
            gload16(gB[q], Bs + ldsOff[q]);
            gA[q] += 32; gB[q] += 32;
        }
        __syncthreads();

        bf16x8 ah[4], al[4], bh[4], bl[4];
        const int sh = lane >> 4;
        #pragma unroll
        for (int i = 0; i < 4; ++i) {
            int row = wm + i * 16 + (lane & 15);
            const unsigned char* base = As + row * 128;
            ah[i] = *(const bf16x8*)(base + ((sh       ^ (row & 7)) << 4));
            al[i] = *(const bf16x8*)(base + (((sh + 4) ^ (row & 7)) << 4));
        }
        #pragma unroll
        for (int j = 0; j < 4; ++j) {
            int row = wn + j * 16 + (lane & 15);
            const unsigned char* base = Bs + row * 128;
            bh[j] = *(const bf16x8*)(base + ((sh       ^ (row & 7)) << 4));
            bl[j] = *(const bf16x8*)(base + (((sh + 4) ^ (row & 7)) << 4));
        }
        #pragma unroll
        for (int i = 0; i < 4; ++i)
            #pragma unroll
            for (int j = 0; j < 4; ++j) {
                acc[i][j] = MFMA16(ah[i], bh[j], acc[i][j]);
                acc[i][j] = MFMA16(ah[i], bl[j], acc[i][j]);
                acc[i][j] = MFMA16(al[i], bh[j], acc[i][j]);
            }
        __syncthreads();
    }

    int km[4];
    #pragma unroll
    for (int j = 0; j < 4; ++j) km[j] = k_mask[b * Ln + n0 + wn + j * 16 + (lane & 15)];
    #pragma unroll
    for (int i = 0; i < 4; ++i) {
        #pragma unroll
        for (int r = 0; r < 4; ++r) {
            int m = m0 + wm + i * 16 + (lane >> 4) * 4 + r;
            float* orow = out_e + ((size_t)(b * Ln + m)) * Ln + n0 + wn;
            #pragma unroll
            for (int j = 0; j < 4; ++j)
                orow[j * 16 + (lane & 15)] = km[j] ? acc[i][j][r] : MASKED_VAL;
        }
    }
}

// ---------------------------------------------------------------------------
// stats: per-row max and 1/sum(exp(e-max)). One wave per row.
// ---------------------------------------------------------------------------
__global__ __launch_bounds__(256) void stats_kernel(const float* __restrict__ e,
                                                    float* __restrict__ stats)
{
    const int row  = blockIdx.x * 4 + (threadIdx.x >> 6);
    const int lane = threadIdx.x & 63;
    const float4* er = (const float4*)(e + (size_t)row * Ln);

    float4 v[8];
    #pragma unroll
    for (int i = 0; i < 8; ++i) v[i] = er[i * 64 + lane];

    float mx = -3.0e38f;
    #pragma unroll
    for (int i = 0; i < 8; ++i)
        mx = fmaxf(mx, fmaxf(fmaxf(v[i].x, v[i].y), fmaxf(v[i].z, v[i].w)));
    #pragma unroll
    for (int o = 32; o > 0; o >>= 1) mx = fmaxf(mx, __shfl_xor(mx, o, 64));

    float s = 0.f;
    #pragma unroll
    for (int i = 0; i < 8; ++i)
        s += __expf(v[i].x - mx) + __expf(v[i].y - mx) +
             __expf(v[i].z - mx) + __expf(v[i].w - mx);
    #pragma unroll
    for (int o = 32; o > 0; o >>= 1) s += __shfl_xor(s, o, 64);

    if (lane == 0) {
        stats[row * 2]     = mx;
        stats[row * 2 + 1] = 1.0f / s;
    }
}

// ---------------------------------------------------------------------------
// pv: a = softmax(e) @ Vp, zero q_mask==0 rows. A=P on the fly (bf16),
// B=Vt via gload_lds. BK=64, single product.
// ---------------------------------------------------------------------------
__global__ __launch_bounds__(256) void pv_kernel(
    const float* __restrict__ e, const u16* __restrict__ Vt,
    const float* __restrict__ stats, const int* __restrict__ q_mask,
    float* __restrict__ out_a)
{
    __shared__ __align__(16) unsigned char As[128 * 128];
    __shared__ __align__(16) unsigned char Bs[128 * 128];

    const int b = blockIdx.z;
    const int m0 = blockIdx.y * 128;   // q tile
    const int n0 = blockIdx.x * 128;   // d tile
    const int tid = threadIdx.x, lane = tid & 63, wid = tid >> 6;
    const int wm = (wid >> 1) * 64, wn = (wid & 1) * 64;

    const float* e_b  = e  + (size_t)b * Ln * Ln;
    const u16*   Vt_b = Vt + (size_t)b * Dn * Ln;

    const int srow = tid >> 1, half = tid & 1;
    const float* srcE = e_b + (size_t)(m0 + srow) * Ln + half * 32;
    const float smx  = stats[(b * Ln + m0 + srow) * 2];
    const float sinv = stats[(b * Ln + m0 + srow) * 2 + 1];
    unsigned char* wA = As + srow * 128;
    int sl[4];
    #pragma unroll
    for (int c = 0; c < 4; ++c) sl[c] = (((half * 4 + c) ^ (srow & 7)) << 4);

    const u16* gB[4];
    #pragma unroll
    for (int q = 0; q < 4; ++q) {
        int c = wid * 4 + q;
        int row = c * 8 + (lane >> 3);
        int sig = (lane & 7) ^ (row & 7);
        gB[q] = Vt_b + (size_t)(n0 + row) * Ln + sig * 8;
    }

    f32x4 acc[4][4];
    const f32x4 z4 = {0.f, 0.f, 0.f, 0.f};
    #pragma unroll
    for (int i = 0; i < 4; ++i)
        #pragma unroll
        for (int j = 0; j < 4; ++j) acc[i][j] = z4;

    for (int k0 = 0; k0 < Ln; k0 += 64) {
        #pragma unroll
        for (int q = 0; q < 4; ++q) {
            gload16(gB[q], Bs + (wid * 4 + q) * 1024);
            gB[q] += 64;
        }
        float fe[32];
        #pragma unroll
        for (int c = 0; c < 8; ++c) *(float4*)&fe[c * 4] = *(const float4*)(srcE + c * 4);
        srcE += 64;
        #pragma unroll
        for (int c = 0; c < 4; ++c) {
            u32 p0 = pack2(__expf(fe[c*8+0] - smx) * sinv, __expf(fe[c*8+1] - smx) * sinv);
            u32 p1 = pack2(__expf(fe[c*8+2] - smx) * sinv, __expf(fe[c*8+3] - smx) * sinv);
            u32 p2 = pack2(__expf(fe[c*8+4] - smx) * sinv, __expf(fe[c*8+5] - smx) * sinv);
            u32 p3 = pack2(__expf(fe[c*8+6] - smx) * sinv, __expf(fe[c*8+7] - smx) * sinv);
            *(uint4*)(wA + sl[c]) = make_uint4(p0, p1, p2, p3);
        }
        __syncthreads();

        const int sh = lane >> 4;
        #pragma unroll
        for (int s = 0; s < 2; ++s) {
            bf16x8 af[4], bv[4];
            #pragma unroll
            for (int i = 0; i < 4; ++i) {
                int row = wm + i * 16 + (lane & 15);
                af[i] = *(const bf16x8*)(As + row * 128 + (((s * 4 + sh) ^ (row & 7)) << 4));
            }
            #pragma unroll
            for (int j = 0; j < 4; ++j) {
                int row = wn + j * 16 + (lane & 15);
                bv[j] = *(const bf16x8*)(Bs + row * 128 + (((s * 4 + sh) ^ (row & 7)) << 4));
            }
            #pragma unroll
            for (int i = 0; i < 4; ++i)
                #pragma unroll
                for (int j = 0; j < 4; ++j)
                    acc[i][j] = MFMA16(af[i], bv[j], acc[i][j]);
        }
        __syncthreads();
    }

    #pragma unroll
    for (int i = 0; i < 4; ++i) {
        #pragma unroll
        for (int r = 0; r < 4; ++r) {
            int m = m0 + wm + i * 16 + (lane >> 4) * 4 + r;
            int qm = q_mask[b * Ln + m];
            float* orow = out_a + (size_t)(b * Ln + m) * Dn + n0 + wn;
            #pragma unroll
            for (int j = 0; j < 4; ++j)
                orow[j * 16 + (lane & 15)] = qm ? acc[i][j][r] : 0.0f;
        }
    }
}

// ---------------------------------------------------------------------------
extern "C" void kernel_launch(void* const* d_in, const int* in_sizes, int n_in,
                              void* d_out, int out_size, void* d_ws, size_t ws_size,
                              hipStream_t stream)
{
    const float* Q  = (const float*)d_in[0];
    const float* K  = (const float*)d_in[1];
    const float* V  = (const float*)d_in[2];
    const float* Wq = (const float*)d_in[3];
    const float* bq = (const float*)d_in[4];
    const float* Wk = (const float*)d_in[5];
    const float* bk = (const float*)d_in[6];
    const float* Wv = (const float*)d_in[7];
    const float* bv = (const float*)d_in[8];
    const int* q_mask = (const int*)d_in[9];
    const int* k_mask = (const int*)d_in[10];

    float* out_a = (float*)d_out;                       // [B, L, D]
    float* out_e = out_a + (size_t)Bn * Ln * Dn;        // [B, L, L]

    const size_t NE = (size_t)Bn * Ln * Dn;             // 16,777,216
    const size_t NW = (size_t)Dn * Dn;                  // 1,048,576

    // ws: Qh Ql Kh Kl Vh [Vbf/Vt alias] Whq Wlq Whk Wlk Whv stats
    u16* Qh  = (u16*)d_ws;
    u16* Ql  = Qh + NE;
    u16* Kh  = Ql + NE;
    u16* Kl  = Kh + NE;
    u16* Vh  = Kl + NE;
    u16* Vbf = Vh + NE;          // dead after projv; Vt aliases it
    u16* Vt  = Vbf;
    u16* Whq = Vbf + NE;
    u16* Wlq = Whq + NW;
    u16* Whk = Wlq + NW;
    u16* Wlk = Whk + NW;
    u16* Whv = Wlk + NW;
    float* stats = (float*)(Whv + NW);

    // out_e region as scratch for Q/K input splits (exactly 4*NE u16 bytes);
    // score overwrites it afterwards.
    u16* Xhq = (u16*)out_e;
    u16* Xlq = Xhq + NE;
    u16* Xhk = Xlq + NE;
    u16* Xlk = Xhk + NE;

    dim3 blk(256);

    // 1) conversions
    convert_split_kernel<<<dim3(NE / 2048), blk, 0, stream>>>(Q, Xhq, Xlq, (int)NE);
    convert_split_kernel<<<dim3(NE / 2048), blk, 0, stream>>>(K, Xhk, Xlk, (int)NE);
    convert_single_kernel<<<dim3(NE / 2048), blk, 0, stream>>>(V, Vbf, (int)NE);
    convert_split_kernel<<<dim3(NW / 2048), blk, 0, stream>>>(Wq, Whq, Wlq, (int)NW);
    convert_split_kernel<<<dim3(NW / 2048), blk, 0, stream>>>(Wk, Whk, Wlk, (int)NW);
    convert_single_kernel<<<dim3(NW / 2048), blk, 0, stream>>>(Wv, Whv, (int)NW);

    // 2) projections
    projqk_kernel<<<dim3(Dn / 128, (Bn * Ln) / 128, 2), blk, 0, stream>>>(
        Xhq, Xlq, Xhk, Xlk, Whq, Wlq, Whk, Wlk, bq, bk, Qh, Ql, Kh, Kl);
    projv_kernel<<<dim3(Dn / 128, (Bn * Ln) / 128), blk, 0, stream>>>(
        Vbf, Whv, bv, Vh);

    // 3) V transpose (Vt aliases the now-dead Vbf)
    vtrans_kernel<<<dim3(Dn / 64, Ln / 64, Bn), blk, 0, stream>>>(Vh, Vt);

    // 4) scores (overwrites the out_e scratch)
    score_kernel<<<dim3(Ln / 128, Ln / 128, Bn), blk, 0, stream>>>(
        Qh, Ql, Kh, Kl, k_mask, out_e);

    // 5) softmax stats
    stats_kernel<<<dim3((Bn * Ln) / 4), blk, 0, stream>>>(out_e, stats);

    // 6) PV
    pv_kernel<<<dim3(Dn / 128, Ln / 128, Bn), blk, 0, stream>>>(
        out_e, Vt, stats, q_mask, out_a);
}